// Round 2
// baseline (431.522 us; speedup 1.0000x reference)
//
#include <hip/hip_runtime.h>

// NCC loss (win=21) on vol [B=2, C=1, X=160, Y=192, Z=160] fp32.
// Separable box sums: K1 products+z-filter -> ws (5 arrays),
// K2 y-filter in place (LDS ring buffer), K3 x-filter + cc + reduce, K4 finalize.

#define B_   2
#define X_   160
#define Y_   192
#define Z_   160
#define WIN_ 21
#define HALF 10
#define YZ   (Y_ * Z_)                       // 30720
#define NTOT ((size_t)B_ * X_ * Y_ * Z_)     // 9830400
#define XSEG 80                              // K3 splits each x-column into 2 segments

// ---------------- K1: products + z-filter (z contiguous; 21-tap from L1) ----------------
__global__ __launch_bounds__(256) void k_prod_zfilt(
    const float* __restrict__ I, const float* __restrict__ J,
    float* __restrict__ F0, float* __restrict__ F1, float* __restrict__ F2,
    float* __restrict__ F3, float* __restrict__ F4)
{
    int t = blockIdx.x * 256 + threadIdx.x;      // exact: 9830400 = 38400*256
    int z = t % Z_;
    const float* Ib = I + (t - z);               // line start
    const float* Jb = J + (t - z);
    float sI = 0.f, sJ = 0.f, sI2 = 0.f, sJ2 = 0.f, sIJ = 0.f;
#pragma unroll
    for (int d = -HALF; d <= HALF; ++d) {
        int zz = z + d;
        if (zz >= 0 && zz < Z_) {
            float a = Ib[zz];
            float b = Jb[zz];
            sI += a; sJ += b;
            sI2 = fmaf(a, a, sI2);
            sJ2 = fmaf(b, b, sJ2);
            sIJ = fmaf(a, b, sIJ);
        }
    }
    F0[t] = sI; F1[t] = sJ; F2[t] = sI2; F3[t] = sJ2; F4[t] = sIJ;
}

// ---------------- K2: y-filter, in place, per-thread column + LDS ring --------------
// grid: (200, 5) — blockIdx.y = channel. Column id = (b*X + x)*Z + z, 51200 total.
__global__ __launch_bounds__(256) void k_yfilt(float* __restrict__ Fall)
{
    __shared__ float ring[WIN_][256];            // [slot][tid]: lane->bank tid%32, 2-way = free
    float* F = Fall + (size_t)blockIdx.y * NTOT;
    int c0  = blockIdx.x * 256 + threadIdx.x;    // [0, 51200)
    int z   = c0 % Z_;
    int sx  = c0 / Z_;                           // b*X + x in [0, 320)
    float* base = F + (size_t)sx * YZ + z;       // element (sx, y=0, z)
    int tid = threadIdx.x;

    // W starts as the window sum at y = -1: raw indices [-11, 9] ∩ [0,Y) = [0,9]
    float W = 0.f;
#pragma unroll
    for (int yy = 0; yy < HALF; ++yy) {
        float v = base[yy * Z_];
        ring[yy][tid] = v;
        W += v;
    }
    int s = HALF;                                // slot of (y+10) at y=0; leaving slot is the same
#pragma unroll 4
    for (int y = 0; y < Y_; ++y) {
        float l = 0.f;
        if (y >= HALF + 1) l = ring[s][tid];     // a[y-11] (read BEFORE overwriting same slot)
        float e = 0.f;
        int ye = y + HALF;
        if (ye < Y_) e = base[ye * Z_];
        ring[s][tid] = e;
        W += e - l;
        base[y * Z_] = W;                        // in place: raw a[y] lives on in the ring
        if (++s == WIN_) s = 0;
    }
}

// ---------------- K3: x-filter + cc + reduction ----------------
// One thread per (b,y,z, segment). Leaving element re-read from global (L2-resident).
__global__ __launch_bounds__(256) void k_xfilt_cc(const float* __restrict__ F,
                                                  double* __restrict__ acc)
{
    const float inv_n = 1.0f / 9261.0f;          // 21^3
    int t   = blockIdx.x * 256 + threadIdx.x;    // [0, 122880) exact: 480*256
    int col = t % (B_ * YZ);                     // [0, 61440)
    int seg = t / (B_ * YZ);
    int z   = col % Z_;
    int y   = (col / Z_) % Y_;
    int b   = col / YZ;
    const float* G = F + (size_t)b * X_ * YZ + (size_t)y * Z_ + z;

    // W starts as the window sum at x = x0-1: raw indices [x0-11, x0+9] ∩ [0,X)
    float W0 = 0.f, W1 = 0.f, W2 = 0.f, W3 = 0.f, W4 = 0.f;
    int x0 = seg * XSEG;
    int pstart = x0 - HALF - 1; if (pstart < 0) pstart = 0;
    int pend = x0 + HALF - 1;                    // inclusive; x0+9 <= 89 < X_ always
    for (int xx = pstart; xx <= pend; ++xx) {
        size_t o = (size_t)xx * YZ;
        W0 += G[o];            W1 += G[o + NTOT];     W2 += G[o + 2 * NTOT];
        W3 += G[o + 3 * NTOT]; W4 += G[o + 4 * NTOT];
    }

    float local = 0.f;
#pragma unroll 2
    for (int x = x0; x < x0 + XSEG; ++x) {
        float e0 = 0.f, e1 = 0.f, e2 = 0.f, e3 = 0.f, e4 = 0.f;
        int xe = x + HALF;
        if (xe < X_) {
            size_t o = (size_t)xe * YZ;
            e0 = G[o];            e1 = G[o + NTOT];     e2 = G[o + 2 * NTOT];
            e3 = G[o + 3 * NTOT]; e4 = G[o + 4 * NTOT];
        }
        int xl = x - HALF - 1;
        if (xl >= 0) {                           // leaving: re-read, hits L2/LLC
            size_t o = (size_t)xl * YZ;
            e0 -= G[o];            e1 -= G[o + NTOT];     e2 -= G[o + 2 * NTOT];
            e3 -= G[o + 3 * NTOT]; e4 -= G[o + 4 * NTOT];
        }
        W0 += e0; W1 += e1; W2 += e2; W3 += e3; W4 += e4;

        float cross = fmaf(-(W0 * W1), inv_n, W4);   // IJ - I*J/n
        float Iv    = fmaf(-(W0 * W0), inv_n, W2);   // I2 - I*I/n
        float Jv    = fmaf(-(W1 * W1), inv_n, W3);   // J2 - J*J/n
        float denom = fmaf(Iv, Jv, 1e-5f);
        local += (cross * cross) / denom;
    }

    // wave (64) shuffle reduce, then cross-wave via LDS, one double atomic per block
#pragma unroll
    for (int off = 32; off > 0; off >>= 1) local += __shfl_down(local, off);
    __shared__ float wsum[4];
    if ((threadIdx.x & 63) == 0) wsum[threadIdx.x >> 6] = local;
    __syncthreads();
    if (threadIdx.x == 0) {
        float s = wsum[0] + wsum[1] + wsum[2] + wsum[3];
        atomicAdd(acc, (double)s);
    }
}

// ---------------- K4: finalize ----------------
__global__ void k_final(const double* __restrict__ acc, float* __restrict__ out)
{
    out[0] = 1.0f - (float)(*acc / (double)(9830400.0));
}

extern "C" void kernel_launch(void* const* d_in, const int* in_sizes, int n_in,
                              void* d_out, int out_size, void* d_ws, size_t ws_size,
                              hipStream_t stream)
{
    const float* I = (const float*)d_in[0];
    const float* J = (const float*)d_in[1];
    float* out = (float*)d_out;

    char* ws = (char*)d_ws;
    double* acc = (double*)ws;                   // 8 B accumulator at offset 0
    float* F = (float*)(ws + 256);               // 5 arrays x 39.3 MB, in-place y-filter

    hipMemsetAsync(acc, 0, sizeof(double), stream);

    k_prod_zfilt<<<dim3((int)(NTOT / 256)), 256, 0, stream>>>(
        I, J, F, F + NTOT, F + 2 * NTOT, F + 3 * NTOT, F + 4 * NTOT);

    k_yfilt<<<dim3(200, 5), 256, 0, stream>>>(F);

    k_xfilt_cc<<<dim3(480), 256, 0, stream>>>(F, acc);

    k_final<<<1, 1, 0, stream>>>(acc, out);
}

// Round 3
// 338.734 us; speedup vs baseline: 1.2739x; 1.2739x over previous
//
#include <hip/hip_runtime.h>

// NCC loss (win=21) on vol [B=2, C=1, X=160, Y=192, Z=160] fp32.
// K1: products + z-filter, 8 outputs/thread, float4 loads, register sliding window.
// K2: y-filter in place (LDS ring). K3: x-filter + cc + reduce. K4: finalize.

#define B_   2
#define X_   160
#define Y_   192
#define Z_   160
#define WIN_ 21
#define HALF 10
#define YZ   (Y_ * Z_)                       // 30720
#define NTOT ((size_t)B_ * X_ * Y_ * Z_)     // 9830400
#define XSEG 80                              // K3 splits each x-column into 2 segments
#define RZ   8                               // K1 outputs per thread
#define CHUNKS (Z_ / RZ)                     // 20

// guarded float4 load: zero-fill outside [0, Z_)
__device__ __forceinline__ float4 ld4_guard(const float* __restrict__ line, int idx)
{
    if (idx >= 0 && idx + 3 < Z_) return *(const float4*)(line + idx);
    float4 r;
    r.x = (idx + 0 >= 0 && idx + 0 < Z_) ? line[idx + 0] : 0.f;
    r.y = (idx + 1 >= 0 && idx + 1 < Z_) ? line[idx + 1] : 0.f;
    r.z = (idx + 2 >= 0 && idx + 2 < Z_) ? line[idx + 2] : 0.f;
    r.w = (idx + 3 >= 0 && idx + 3 < Z_) ? line[idx + 3] : 0.f;
    return r;
}

// ---------------- K1: products + z-filter, 8 outputs / thread ----------------
__global__ __launch_bounds__(256) void k_prod_zfilt(
    const float* __restrict__ I, const float* __restrict__ J,
    float* __restrict__ F0, float* __restrict__ F1, float* __restrict__ F2,
    float* __restrict__ F3, float* __restrict__ F4)
{
    int t = blockIdx.x * 256 + threadIdx.x;      // 1,228,800 threads = 4800 * 256
    int chunk = t % CHUNKS;
    int line  = t / CHUNKS;                      // b*X*Y + x*Y... (flattened B*X*Y lines)
    int z0 = chunk * RZ;
    const float* Ib = I + (size_t)line * Z_;
    const float* Jb = J + (size_t)line * Z_;

    // raw span [z0-12, z0+19], local L <-> raw z0-12+L
    float a[32], b[32];
    int zb = z0 - 12;
#pragma unroll
    for (int i = 0; i < 8; ++i) {
        float4 va = ld4_guard(Ib, zb + 4 * i);
        float4 vb = ld4_guard(Jb, zb + 4 * i);
        a[4 * i + 0] = va.x; a[4 * i + 1] = va.y; a[4 * i + 2] = va.z; a[4 * i + 3] = va.w;
        b[4 * i + 0] = vb.x; b[4 * i + 1] = vb.y; b[4 * i + 2] = vb.z; b[4 * i + 3] = vb.w;
    }

    // first window (output r=0): raw [z0-10, z0+10] -> local [2, 22]
    float sI = 0.f, sJ = 0.f, sI2 = 0.f, sJ2 = 0.f, sIJ = 0.f;
#pragma unroll
    for (int k = 2; k <= 22; ++k) {
        float x = a[k], y = b[k];
        sI += x; sJ += y;
        sI2 = fmaf(x, x, sI2);
        sJ2 = fmaf(y, y, sJ2);
        sIJ = fmaf(x, y, sIJ);
    }
    float oI[RZ], oJ[RZ], oI2[RZ], oJ2[RZ], oIJ[RZ];
    oI[0] = sI; oJ[0] = sJ; oI2[0] = sI2; oJ2[0] = sJ2; oIJ[0] = sIJ;
#pragma unroll
    for (int r = 1; r < RZ; ++r) {
        float ae = a[r + 22], al = a[r + 1];     // entering raw z0+r+10, leaving raw z0+r-11
        float be = b[r + 22], bl = b[r + 1];
        sI += ae - al;
        sJ += be - bl;
        sI2 += fmaf(ae, ae, -(al * al));
        sJ2 += fmaf(be, be, -(bl * bl));
        sIJ += fmaf(ae, be, -(al * bl));
        oI[r] = sI; oJ[r] = sJ; oI2[r] = sI2; oJ2[r] = sJ2; oIJ[r] = sIJ;
    }

    size_t o = (size_t)line * Z_ + z0;           // 16B-aligned (z0 multiple of 8)
    *(float4*)(F0 + o)     = make_float4(oI[0],  oI[1],  oI[2],  oI[3]);
    *(float4*)(F0 + o + 4) = make_float4(oI[4],  oI[5],  oI[6],  oI[7]);
    *(float4*)(F1 + o)     = make_float4(oJ[0],  oJ[1],  oJ[2],  oJ[3]);
    *(float4*)(F1 + o + 4) = make_float4(oJ[4],  oJ[5],  oJ[6],  oJ[7]);
    *(float4*)(F2 + o)     = make_float4(oI2[0], oI2[1], oI2[2], oI2[3]);
    *(float4*)(F2 + o + 4) = make_float4(oI2[4], oI2[5], oI2[6], oI2[7]);
    *(float4*)(F3 + o)     = make_float4(oJ2[0], oJ2[1], oJ2[2], oJ2[3]);
    *(float4*)(F3 + o + 4) = make_float4(oJ2[4], oJ2[5], oJ2[6], oJ2[7]);
    *(float4*)(F4 + o)     = make_float4(oIJ[0], oIJ[1], oIJ[2], oIJ[3]);
    *(float4*)(F4 + o + 4) = make_float4(oIJ[4], oIJ[5], oIJ[6], oIJ[7]);
}

// ---------------- K2: y-filter, in place, per-thread column + LDS ring --------------
// grid: (200, 5) — blockIdx.y = channel. Column id = (b*X + x)*Z + z, 51200 total.
__global__ __launch_bounds__(256) void k_yfilt(float* __restrict__ Fall)
{
    __shared__ float ring[WIN_][256];            // [slot][tid]: 2 lanes/bank = free
    float* F = Fall + (size_t)blockIdx.y * NTOT;
    int c0  = blockIdx.x * 256 + threadIdx.x;    // [0, 51200)
    int z   = c0 % Z_;
    int sx  = c0 / Z_;                           // b*X + x in [0, 320)
    float* base = F + (size_t)sx * YZ + z;       // element (sx, y=0, z)
    int tid = threadIdx.x;

    // W = window sum at y = -1: raw indices [-11, 9] ∩ [0,Y) = [0,9]
    float W = 0.f;
#pragma unroll
    for (int yy = 0; yy < HALF; ++yy) {
        float v = base[yy * Z_];
        ring[yy][tid] = v;
        W += v;
    }
    int s = HALF;
#pragma unroll 4
    for (int y = 0; y < Y_; ++y) {
        float l = 0.f;
        if (y >= HALF + 1) l = ring[s][tid];     // a[y-11] (read BEFORE overwrite)
        float e = 0.f;
        int ye = y + HALF;
        if (ye < Y_) e = base[ye * Z_];
        ring[s][tid] = e;
        W += e - l;
        base[y * Z_] = W;                        // in place: raw a[y] lives on in ring
        if (++s == WIN_) s = 0;
    }
}

// ---------------- K3: x-filter + cc + reduction ----------------
__global__ __launch_bounds__(256) void k_xfilt_cc(const float* __restrict__ F,
                                                  double* __restrict__ acc)
{
    const float inv_n = 1.0f / 9261.0f;          // 21^3
    int t   = blockIdx.x * 256 + threadIdx.x;    // [0, 122880)
    int col = t % (B_ * YZ);
    int seg = t / (B_ * YZ);
    int z   = col % Z_;
    int y   = (col / Z_) % Y_;
    int b   = col / YZ;
    const float* G = F + (size_t)b * X_ * YZ + (size_t)y * Z_ + z;

    // W = window sum at x = x0-1: raw [x0-11, x0+9] ∩ [0,X)
    float W0 = 0.f, W1 = 0.f, W2 = 0.f, W3 = 0.f, W4 = 0.f;
    int x0 = seg * XSEG;
    int pstart = x0 - HALF - 1; if (pstart < 0) pstart = 0;
    int pend = x0 + HALF - 1;
    for (int xx = pstart; xx <= pend; ++xx) {
        size_t o = (size_t)xx * YZ;
        W0 += G[o];            W1 += G[o + NTOT];     W2 += G[o + 2 * NTOT];
        W3 += G[o + 3 * NTOT]; W4 += G[o + 4 * NTOT];
    }

    float local = 0.f;
#pragma unroll 2
    for (int x = x0; x < x0 + XSEG; ++x) {
        float e0 = 0.f, e1 = 0.f, e2 = 0.f, e3 = 0.f, e4 = 0.f;
        int xe = x + HALF;
        if (xe < X_) {
            size_t o = (size_t)xe * YZ;
            e0 = G[o];            e1 = G[o + NTOT];     e2 = G[o + 2 * NTOT];
            e3 = G[o + 3 * NTOT]; e4 = G[o + 4 * NTOT];
        }
        int xl = x - HALF - 1;
        if (xl >= 0) {
            size_t o = (size_t)xl * YZ;
            e0 -= G[o];            e1 -= G[o + NTOT];     e2 -= G[o + 2 * NTOT];
            e3 -= G[o + 3 * NTOT]; e4 -= G[o + 4 * NTOT];
        }
        W0 += e0; W1 += e1; W2 += e2; W3 += e3; W4 += e4;

        float cross = fmaf(-(W0 * W1), inv_n, W4);
        float Iv    = fmaf(-(W0 * W0), inv_n, W2);
        float Jv    = fmaf(-(W1 * W1), inv_n, W3);
        float denom = fmaf(Iv, Jv, 1e-5f);
        local += (cross * cross) / denom;
    }

#pragma unroll
    for (int off = 32; off > 0; off >>= 1) local += __shfl_down(local, off);
    __shared__ float wsum[4];
    if ((threadIdx.x & 63) == 0) wsum[threadIdx.x >> 6] = local;
    __syncthreads();
    if (threadIdx.x == 0) {
        float s = wsum[0] + wsum[1] + wsum[2] + wsum[3];
        atomicAdd(acc, (double)s);
    }
}

// ---------------- K4: finalize ----------------
__global__ void k_final(const double* __restrict__ acc, float* __restrict__ out)
{
    out[0] = 1.0f - (float)(*acc / (double)(9830400.0));
}

extern "C" void kernel_launch(void* const* d_in, const int* in_sizes, int n_in,
                              void* d_out, int out_size, void* d_ws, size_t ws_size,
                              hipStream_t stream)
{
    const float* I = (const float*)d_in[0];
    const float* J = (const float*)d_in[1];
    float* out = (float*)d_out;

    char* ws = (char*)d_ws;
    double* acc = (double*)ws;
    float* F = (float*)(ws + 256);

    hipMemsetAsync(acc, 0, sizeof(double), stream);

    k_prod_zfilt<<<dim3((int)(NTOT / RZ / 256)), 256, 0, stream>>>(
        I, J, F, F + NTOT, F + 2 * NTOT, F + 3 * NTOT, F + 4 * NTOT);

    k_yfilt<<<dim3(200, 5), 256, 0, stream>>>(F);

    k_xfilt_cc<<<dim3(480), 256, 0, stream>>>(F, acc);

    k_final<<<1, 1, 0, stream>>>(acc, out);
}

// Round 4
// 323.269 us; speedup vs baseline: 1.3349x; 1.0478x over previous
//
#include <hip/hip_runtime.h>

// NCC loss (win=21) on vol [B=2, C=1, X=160, Y=192, Z=160] fp32.
// K1: products + z-filter, 8 outputs/thread, float4 loads, register sliding window;
//     dual-writes raw rows y in [94,114] to side buffer S (race-free y-segmentation).
// K2: y-filter in place (LDS ring), 2 y-segments, overlap raws read from S.
// K3: x-filter + cc + reduce, 4 x-segments. K4: finalize.

#define B_   2
#define X_   160
#define Y_   192
#define Z_   160
#define WIN_ 21
#define HALF 10
#define YZ   (Y_ * Z_)                       // 30720
#define NTOT ((size_t)B_ * X_ * Y_ * Z_)     // 9830400
#define XSEG 40                              // K3: 4 x-segments
#define RZ   8                               // K1 outputs per thread
#define CHUNKS (Z_ / RZ)                     // 20
#define SXN  (B_ * X_)                       // 320 (b*X + x)
#define YSEG0 105                            // 5*21: keeps ring phase uniform across segs
#define OVLO 94                              // overlap rows [94,114] mirrored in S
#define OVHI 114

// vector-or-zero load. Vectors start at idx ≡ 0 (mod 4) and Z_ ≡ 0 (mod 4),
// so a float4 is always FULLY in-bounds or FULLY out — no partial path needed.
__device__ __forceinline__ float4 ld4z(const float* __restrict__ line, int idx)
{
    if (idx >= 0 && idx < Z_) return *(const float4*)(line + idx);
    return make_float4(0.f, 0.f, 0.f, 0.f);
}

// ---------------- K1: products + z-filter, 8 outputs / thread ----------------
__global__ __launch_bounds__(256) void k_prod_zfilt(
    const float* __restrict__ I, const float* __restrict__ J,
    float* __restrict__ F, float* __restrict__ S)
{
    int t = blockIdx.x * 256 + threadIdx.x;      // 1,228,800 threads = 4800 * 256
    int chunk = t % CHUNKS;
    int line  = t / CHUNKS;                      // (b*X + x)*Y + y
    int z0 = chunk * RZ;
    const float* Ib = I + (size_t)line * Z_;
    const float* Jb = J + (size_t)line * Z_;

    // raw span [z0-12, z0+19], local L <-> raw z0-12+L
    float a[32], b[32];
    int zb = z0 - 12;
#pragma unroll
    for (int i = 0; i < 8; ++i) {
        float4 va = ld4z(Ib, zb + 4 * i);
        float4 vb = ld4z(Jb, zb + 4 * i);
        a[4 * i + 0] = va.x; a[4 * i + 1] = va.y; a[4 * i + 2] = va.z; a[4 * i + 3] = va.w;
        b[4 * i + 0] = vb.x; b[4 * i + 1] = vb.y; b[4 * i + 2] = vb.z; b[4 * i + 3] = vb.w;
    }

    // first window (output r=0): raw [z0-10, z0+10] -> local [2, 22]
    float sI = 0.f, sJ = 0.f, sI2 = 0.f, sJ2 = 0.f, sIJ = 0.f;
#pragma unroll
    for (int k = 2; k <= 22; ++k) {
        float x = a[k], y = b[k];
        sI += x; sJ += y;
        sI2 = fmaf(x, x, sI2);
        sJ2 = fmaf(y, y, sJ2);
        sIJ = fmaf(x, y, sIJ);
    }
    float o0[RZ], o1[RZ], o2[RZ], o3[RZ], o4[RZ];
    o0[0] = sI; o1[0] = sJ; o2[0] = sI2; o3[0] = sJ2; o4[0] = sIJ;
#pragma unroll
    for (int r = 1; r < RZ; ++r) {
        float ae = a[r + 22], al = a[r + 1];     // entering raw z0+r+10, leaving z0+r-11
        float be = b[r + 22], bl = b[r + 1];
        sI += ae - al;
        sJ += be - bl;
        sI2 += fmaf(ae, ae, -(al * al));
        sJ2 += fmaf(be, be, -(bl * bl));
        sIJ += fmaf(ae, be, -(al * bl));
        o0[r] = sI; o1[r] = sJ; o2[r] = sI2; o3[r] = sJ2; o4[r] = sIJ;
    }

    size_t o = (size_t)line * Z_ + z0;           // 16B-aligned
    float* dst[5] = { F, F + NTOT, F + 2 * NTOT, F + 3 * NTOT, F + 4 * NTOT };
    float* arr[5] = { o0, o1, o2, o3, o4 };
#pragma unroll
    for (int c = 0; c < 5; ++c) {
        float* p = arr[c];
        *(float4*)(dst[c] + o)     = make_float4(p[0], p[1], p[2], p[3]);
        *(float4*)(dst[c] + o + 4) = make_float4(p[4], p[5], p[6], p[7]);
    }

    // mirror overlap rows to S[ch][sx][y-94][z]  (raw copies for K2's y-segmentation)
    int y  = line % Y_;
    int sx = line / Y_;
    if (y >= OVLO && y <= OVHI) {
#pragma unroll
        for (int c = 0; c < 5; ++c) {
            float* p = arr[c];
            size_t so = (((size_t)c * SXN + sx) * WIN_ + (y - OVLO)) * Z_ + z0;
            *(float4*)(S + so)     = make_float4(p[0], p[1], p[2], p[3]);
            *(float4*)(S + so + 4) = make_float4(p[4], p[5], p[6], p[7]);
        }
    }
}

// ---------------- K2: y-filter, in place, 2 y-segments, LDS ring --------------
// grid: (400, 5) — blockIdx.x%200 -> column tile, /200 -> y-segment, .y = channel.
__global__ __launch_bounds__(256) void k_yfilt(float* __restrict__ Fall,
                                               const float* __restrict__ S)
{
    __shared__ float ring[WIN_][256];            // [slot][tid]: 2 lanes/bank = free
    int seg = blockIdx.x / 200;
    int c0  = (blockIdx.x % 200) * 256 + threadIdx.x;   // [0, 51200)
    int ch  = blockIdx.y;
    int z   = c0 % Z_;
    int sx  = c0 / Z_;                           // [0, 320)
    float* Fb = Fall + (size_t)ch * NTOT + (size_t)sx * YZ + z;      // (sx, y=0, z)
    const float* Sb = S + (((size_t)ch * SXN + sx) * WIN_) * Z_ + z; // row i = raw y 94+i
    int tid = threadIdx.x;
    int y0    = seg ? YSEG0 : 0;
    int y_end = seg ? Y_ : YSEG0;

    // preload ring with raw [y0-11, y0+9] (clipped); slot = idx % 21. W = their sum.
    float W = 0.f;
#pragma unroll
    for (int i = 0; i < WIN_; ++i) {
        int idx = y0 - 11 + i;                   // <= y0+9 <= 114 < Y_ always
        if (idx >= 0) {
            float v = (idx >= OVLO) ? Sb[(idx - OVLO) * Z_] : Fb[idx * Z_];
            ring[idx % WIN_][tid] = v;
            W += v;
        }
    }
    int s = (y0 + HALF) % WIN_;                  // = 10 for both segs (y0 % 21 == 0)
#pragma unroll 4
    for (int y = y0; y < y_end; ++y) {
        float l = 0.f;
        if (y >= HALF + 1) l = ring[s][tid];     // raw y-11 (read BEFORE overwrite)
        float e = 0.f;
        int ye = y + HALF;
        if (ye < Y_)                             // raw y+10; overlap rows come from S
            e = (ye >= OVLO && ye <= OVHI) ? Sb[(ye - OVLO) * Z_] : Fb[ye * Z_];
        ring[s][tid] = e;
        W += e - l;
        Fb[y * Z_] = W;                          // in place: raw lives on in ring/S
        if (++s == WIN_) s = 0;
    }
}

// ---------------- K3: x-filter + cc + reduction (4 x-segments) ----------------
__global__ __launch_bounds__(256) void k_xfilt_cc(const float* __restrict__ F,
                                                  double* __restrict__ acc)
{
    const float inv_n = 1.0f / 9261.0f;          // 21^3
    int t   = blockIdx.x * 256 + threadIdx.x;    // [0, 245760) = 960*256
    int col = t % (B_ * YZ);                     // wave-uniform seg (61440 % 256 == 0)
    int seg = t / (B_ * YZ);
    int z   = col % Z_;
    int y   = (col / Z_) % Y_;
    int b   = col / YZ;
    const float* G = F + (size_t)b * X_ * YZ + (size_t)y * Z_ + z;

    // W = window sum at x = x0-1: raw [x0-11, x0+9] ∩ [0,X)
    float W0 = 0.f, W1 = 0.f, W2 = 0.f, W3 = 0.f, W4 = 0.f;
    int x0 = seg * XSEG;
    int pstart = x0 - HALF - 1; if (pstart < 0) pstart = 0;
    int pend = x0 + HALF - 1;                    // <= 130+... always < X_ for x0<=120
    for (int xx = pstart; xx <= pend; ++xx) {
        size_t o = (size_t)xx * YZ;
        W0 += G[o];            W1 += G[o + NTOT];     W2 += G[o + 2 * NTOT];
        W3 += G[o + 3 * NTOT]; W4 += G[o + 4 * NTOT];
    }

    float local = 0.f;
#pragma unroll 4
    for (int x = x0; x < x0 + XSEG; ++x) {
        float e0 = 0.f, e1 = 0.f, e2 = 0.f, e3 = 0.f, e4 = 0.f;
        int xe = x + HALF;
        if (xe < X_) {
            size_t o = (size_t)xe * YZ;
            e0 = G[o];            e1 = G[o + NTOT];     e2 = G[o + 2 * NTOT];
            e3 = G[o + 3 * NTOT]; e4 = G[o + 4 * NTOT];
        }
        int xl = x - HALF - 1;
        if (xl >= 0) {                           // leaving re-read: L2/LLC-resident
            size_t o = (size_t)xl * YZ;
            e0 -= G[o];            e1 -= G[o + NTOT];     e2 -= G[o + 2 * NTOT];
            e3 -= G[o + 3 * NTOT]; e4 -= G[o + 4 * NTOT];
        }
        W0 += e0; W1 += e1; W2 += e2; W3 += e3; W4 += e4;

        float cross = fmaf(-(W0 * W1), inv_n, W4);
        float Iv    = fmaf(-(W0 * W0), inv_n, W2);
        float Jv    = fmaf(-(W1 * W1), inv_n, W3);
        float denom = fmaf(Iv, Jv, 1e-5f);
        local += (cross * cross) / denom;
    }

#pragma unroll
    for (int off = 32; off > 0; off >>= 1) local += __shfl_down(local, off);
    __shared__ float wsum[4];
    if ((threadIdx.x & 63) == 0) wsum[threadIdx.x >> 6] = local;
    __syncthreads();
    if (threadIdx.x == 0) {
        float sm = wsum[0] + wsum[1] + wsum[2] + wsum[3];
        atomicAdd(acc, (double)sm);
    }
}

// ---------------- K4: finalize ----------------
__global__ void k_final(const double* __restrict__ acc, float* __restrict__ out)
{
    out[0] = 1.0f - (float)(*acc / (double)(9830400.0));
}

extern "C" void kernel_launch(void* const* d_in, const int* in_sizes, int n_in,
                              void* d_out, int out_size, void* d_ws, size_t ws_size,
                              hipStream_t stream)
{
    const float* I = (const float*)d_in[0];
    const float* J = (const float*)d_in[1];
    float* out = (float*)d_out;

    char* ws = (char*)d_ws;
    double* acc = (double*)ws;                   // 8 B
    float* F = (float*)(ws + 256);               // 5 x 39.3 MB
    float* S = F + 5 * NTOT;                     // 5*320*21*160*4 B = 21.5 MB

    hipMemsetAsync(acc, 0, sizeof(double), stream);

    k_prod_zfilt<<<dim3((int)(NTOT / RZ / 256)), 256, 0, stream>>>(I, J, F, S);

    k_yfilt<<<dim3(400, 5), 256, 0, stream>>>(F, S);

    k_xfilt_cc<<<dim3(960), 256, 0, stream>>>(F, acc);

    k_final<<<1, 1, 0, stream>>>(acc, out);
}